// Round 1
// baseline (531.393 us; speedup 1.0000x reference)
//
#include <hip/hip_runtime.h>

#define N_NODES 10000
#define E_EDGES 640000
#define IN_CH   512
#define OUT_CH  256

// ---------------- degree histogram ----------------
__global__ void deg_kernel(const int* __restrict__ row, int* __restrict__ deg, int E) {
    int e = blockIdx.x * blockDim.x + threadIdx.x;
    if (e < E) atomicAdd(&deg[row[e]], 1);
}

// ---------------- dinv = rsqrt(deg) ----------------
__global__ void dinv_kernel(const int* __restrict__ deg, float* __restrict__ dinv, int n) {
    int i = blockIdx.x * blockDim.x + threadIdx.x;
    if (i < n) {
        int d = deg[i];
        dinv[i] = (d > 0) ? rsqrtf((float)d) : 0.0f;
    }
}

// ---------------- single-block exclusive scan over deg -> offs[n+1] ----------------
__global__ void scan_kernel(const int* __restrict__ deg, int* __restrict__ offs, int n) {
    __shared__ int partial[256];
    int tid = threadIdx.x;
    int per = (n + 255) / 256;
    int start = tid * per;
    int end = start + per; if (end > n) end = n; if (start > n) start = n;
    int s = 0;
    for (int i = start; i < end; i++) s += deg[i];
    partial[tid] = s;
    __syncthreads();
    // Hillis-Steele inclusive scan
    for (int off = 1; off < 256; off <<= 1) {
        int v = (tid >= off) ? partial[tid - off] : 0;
        __syncthreads();
        partial[tid] += v;
        __syncthreads();
    }
    int base = (tid == 0) ? 0 : partial[tid - 1];
    for (int i = start; i < end; i++) {
        offs[i] = base;
        base += deg[i];
    }
    if (tid == 255) offs[n] = partial[255];
}

// ---------------- scatter edges into CSR ----------------
__global__ void scatter_kernel(const int* __restrict__ row, const int* __restrict__ col,
                               const float* __restrict__ dinv, const int* __restrict__ offs,
                               int* __restrict__ cursor, int* __restrict__ csr_col,
                               float* __restrict__ csr_norm, int E) {
    int e = blockIdx.x * blockDim.x + threadIdx.x;
    if (e >= E) return;
    int r = row[e];
    int c = col[e];
    int p = offs[r] + atomicAdd(&cursor[r], 1);
    csr_col[p] = c;
    csr_norm[p] = dinv[r] * dinv[c];
}

// ---------------- fp32 tiled GEMM: out[i][c] = sum_k x[i][k]*w[c][k] + b[c] ----------------
#define BM 64
#define BN 64
#define BK 32
__global__ __launch_bounds__(256) void gemm_kernel(const float* __restrict__ x,
                                                   const float* __restrict__ w,
                                                   const float* __restrict__ bias,
                                                   float* __restrict__ out, int M) {
    __shared__ float As[BK][BM + 1];
    __shared__ float Bs[BK][BN + 1];
    int tid = threadIdx.x;
    int tx = tid & 15, ty = tid >> 4;
    int row0 = blockIdx.x * BM;
    int col0 = blockIdx.y * BN;
    float acc[4][4] = {};
    for (int k0 = 0; k0 < IN_CH; k0 += BK) {
        #pragma unroll
        for (int i = 0; i < 8; i++) {
            int idx = tid + i * 256;
            int m = idx >> 5, kk = idx & 31;
            int r = row0 + m;
            As[kk][m] = (r < M) ? x[r * IN_CH + k0 + kk] : 0.0f;
        }
        #pragma unroll
        for (int i = 0; i < 8; i++) {
            int idx = tid + i * 256;
            int c = idx >> 5, kk = idx & 31;
            Bs[kk][c] = w[(col0 + c) * IN_CH + k0 + kk];
        }
        __syncthreads();
        #pragma unroll
        for (int kk = 0; kk < BK; kk++) {
            float a[4], b[4];
            #pragma unroll
            for (int i = 0; i < 4; i++) a[i] = As[kk][ty * 4 + i];
            #pragma unroll
            for (int j = 0; j < 4; j++) b[j] = Bs[kk][tx * 4 + j];
            #pragma unroll
            for (int i = 0; i < 4; i++)
                #pragma unroll
                for (int j = 0; j < 4; j++)
                    acc[i][j] += a[i] * b[j];
        }
        __syncthreads();
    }
    #pragma unroll
    for (int i = 0; i < 4; i++) {
        int r = row0 + ty * 4 + i;
        if (r < M) {
            #pragma unroll
            for (int j = 0; j < 4; j++) {
                int c = col0 + tx * 4 + j;
                out[r * OUT_CH + c] = acc[i][j] + bias[c];
            }
        }
    }
}

// ---------------- SpMM: one wave per node, lane owns 4 channels (float4) ----------------
// y_i = sum_{e in CSR[i]} norm_e * h[col_e]
// if y_out   : y_out[i] = y_i
// if axpy_out: axpy_out[i] = prev[i] + wts[widx] * y_i
__global__ __launch_bounds__(256) void spmm_kernel(const float* __restrict__ h,
                                                   const int* __restrict__ offs,
                                                   const int* __restrict__ csr_col,
                                                   const float* __restrict__ csr_norm,
                                                   const float* __restrict__ prev,
                                                   const float* __restrict__ wts, int widx,
                                                   float* __restrict__ y_out,
                                                   float* __restrict__ axpy_out, int n) {
    int wave = (blockIdx.x * blockDim.x + threadIdx.x) >> 6;
    int lane = threadIdx.x & 63;
    if (wave >= n) return;
    int node = wave;
    int s = offs[node], e = offs[node + 1];
    float4 acc = make_float4(0.f, 0.f, 0.f, 0.f);
    for (int p = s; p < e; p++) {
        int c = csr_col[p];
        float nm = csr_norm[p];
        float4 v = ((const float4*)(h + (size_t)c * OUT_CH))[lane];
        acc.x += nm * v.x;
        acc.y += nm * v.y;
        acc.z += nm * v.z;
        acc.w += nm * v.w;
    }
    if (y_out) {
        ((float4*)(y_out + (size_t)node * OUT_CH))[lane] = acc;
    }
    if (axpy_out) {
        float wk = wts[widx];
        float4 pv = ((const float4*)(prev + (size_t)node * OUT_CH))[lane];
        float4 o;
        o.x = pv.x + wk * acc.x;
        o.y = pv.y + wk * acc.y;
        o.z = pv.z + wk * acc.z;
        o.w = pv.w + wk * acc.w;
        ((float4*)(axpy_out + (size_t)node * OUT_CH))[lane] = o;
    }
}

extern "C" void kernel_launch(void* const* d_in, const int* in_sizes, int n_in,
                              void* d_out, int out_size, void* d_ws, size_t ws_size,
                              hipStream_t stream) {
    const float* x     = (const float*)d_in[0];
    const int*   ei    = (const int*)d_in[1];   // [2, E]: row = ei[0..E), col = ei[E..2E)
    const float* lin_w = (const float*)d_in[2]; // [OUT_CH, IN_CH]
    const float* lin_b = (const float*)d_in[3]; // [OUT_CH]
    const float* wts   = (const float*)d_in[4]; // [K]
    float* out = (float*)d_out;

    char* ws = (char*)d_ws;
    size_t off = 0;
    auto alloc = [&](size_t bytes) -> void* {
        void* p = ws + off;
        off += (bytes + 255) & ~(size_t)255;
        return p;
    };
    int*   deg      = (int*)  alloc(N_NODES * 4);
    int*   cursor   = (int*)  alloc(N_NODES * 4);
    int*   offs     = (int*)  alloc((N_NODES + 1) * 4);
    float* dinv     = (float*)alloc(N_NODES * 4);
    int*   csr_col  = (int*)  alloc((size_t)E_EDGES * 4);
    float* csr_norm = (float*)alloc((size_t)E_EDGES * 4);
    float* h0       = (float*)alloc((size_t)N_NODES * OUT_CH * 4);
    float* out1     = (float*)alloc((size_t)N_NODES * OUT_CH * 4);
    float* t2       = (float*)alloc((size_t)N_NODES * OUT_CH * 4);

    hipMemsetAsync(deg, 0, N_NODES * 4, stream);
    hipMemsetAsync(cursor, 0, N_NODES * 4, stream);

    const int* row = ei;
    const int* col = ei + E_EDGES;

    deg_kernel<<<(E_EDGES + 255) / 256, 256, 0, stream>>>(row, deg, E_EDGES);
    dinv_kernel<<<(N_NODES + 255) / 256, 256, 0, stream>>>(deg, dinv, N_NODES);
    scan_kernel<<<1, 256, 0, stream>>>(deg, offs, N_NODES);
    scatter_kernel<<<(E_EDGES + 255) / 256, 256, 0, stream>>>(row, col, dinv, offs, cursor,
                                                              csr_col, csr_norm, E_EDGES);

    dim3 ggrid((N_NODES + BM - 1) / BM, OUT_CH / BN);
    gemm_kernel<<<ggrid, 256, 0, stream>>>(x, lin_w, lin_b, h0, N_NODES);

    int sgrid = (N_NODES + 3) / 4; // 4 waves (nodes) per 256-thread block
    // out1 = h0 + w0 * spmm(h0)
    spmm_kernel<<<sgrid, 256, 0, stream>>>(h0, offs, csr_col, csr_norm, h0, wts, 0,
                                           nullptr, out1, N_NODES);
    // t2 = spmm(out1)
    spmm_kernel<<<sgrid, 256, 0, stream>>>(out1, offs, csr_col, csr_norm, nullptr, wts, 0,
                                           t2, nullptr, N_NODES);
    // out = out1 + w1 * spmm(t2)
    spmm_kernel<<<sgrid, 256, 0, stream>>>(t2, offs, csr_col, csr_norm, out1, wts, 1,
                                           nullptr, out, N_NODES);
}

// Round 2
// 379.159 us; speedup vs baseline: 1.4015x; 1.4015x over previous
//
#include <hip/hip_runtime.h>

#define N_NODES 10000
#define E_EDGES 640000
#define IN_CH   512
#define OUT_CH  256

typedef short bf16x8 __attribute__((ext_vector_type(8)));
typedef float f32x4  __attribute__((ext_vector_type(4)));

__device__ __forceinline__ float bf2f(unsigned short u) {
    return __uint_as_float(((unsigned int)u) << 16);
}
__device__ __forceinline__ unsigned short f2b(float f) {
    unsigned int u = __float_as_uint(f);
    return (unsigned short)((u + 0x7FFFu + ((u >> 16) & 1u)) >> 16);
}

// ---------------- degree histogram ----------------
__global__ void deg_kernel(const int* __restrict__ row, int* __restrict__ deg, int E) {
    int e = blockIdx.x * blockDim.x + threadIdx.x;
    if (e < E) atomicAdd(&deg[row[e]], 1);
}

// ---------------- dinv = rsqrt(deg) ----------------
__global__ void dinv_kernel(const int* __restrict__ deg, float* __restrict__ dinv, int n) {
    int i = blockIdx.x * blockDim.x + threadIdx.x;
    if (i < n) {
        int d = deg[i];
        dinv[i] = (d > 0) ? rsqrtf((float)d) : 0.0f;
    }
}

// ---------------- single-block exclusive scan over deg -> offs[n+1] ----------------
__global__ void scan_kernel(const int* __restrict__ deg, int* __restrict__ offs, int n) {
    __shared__ int partial[256];
    int tid = threadIdx.x;
    int per = (n + 255) / 256;
    int start = tid * per;
    int end = start + per; if (end > n) end = n; if (start > n) start = n;
    int s = 0;
    for (int i = start; i < end; i++) s += deg[i];
    partial[tid] = s;
    __syncthreads();
    for (int off = 1; off < 256; off <<= 1) {
        int v = (tid >= off) ? partial[tid - off] : 0;
        __syncthreads();
        partial[tid] += v;
        __syncthreads();
    }
    int base = (tid == 0) ? 0 : partial[tid - 1];
    for (int i = start; i < end; i++) {
        offs[i] = base;
        base += deg[i];
    }
    if (tid == 255) offs[n] = partial[255];
}

// ---------------- scatter edges into CSR ----------------
__global__ void scatter_kernel(const int* __restrict__ row, const int* __restrict__ col,
                               const float* __restrict__ dinv, const int* __restrict__ offs,
                               int* __restrict__ cursor, int* __restrict__ csr_col,
                               float* __restrict__ csr_norm, int E) {
    int e = blockIdx.x * blockDim.x + threadIdx.x;
    if (e >= E) return;
    int r = row[e];
    int c = col[e];
    int p = offs[r] + atomicAdd(&cursor[r], 1);
    csr_col[p] = c;
    csr_norm[p] = dinv[r] * dinv[c];
}

// ---------------- fp32 -> bf16 conversion (vectorized) ----------------
__global__ void cvt_kernel(const float* __restrict__ src, unsigned short* __restrict__ dst, int n4) {
    int i = blockIdx.x * blockDim.x + threadIdx.x;
    if (i >= n4) return;
    float4 v = ((const float4*)src)[i];
    ushort4 o;
    o.x = f2b(v.x); o.y = f2b(v.y); o.z = f2b(v.z); o.w = f2b(v.w);
    ((ushort4*)dst)[i] = o;
}

// ---------------- bf16 MFMA GEMM: h0[m][n] = sum_k x[m][k]*w[n][k] + b[n] ----------------
// Block tile 64(M) x 128(N): 4 waves, wave w does rows [w*16, w*16+16) x 128 cols.
// A frag: lane holds A[m=l16][k=quad*8+j]; B frag (B^T input): lane holds B[n=l16][k=quad*8+j].
// D layout: col = l16, row = quad*4 + reg.
__global__ __launch_bounds__(256) void gemm_mfma(const unsigned short* __restrict__ xb,
                                                 const unsigned short* __restrict__ wb,
                                                 const float* __restrict__ bias,
                                                 float* __restrict__ h0,
                                                 unsigned short* __restrict__ h0b, int M) {
    int wave = threadIdx.x >> 6;
    int lane = threadIdx.x & 63;
    int quad = lane >> 4;
    int l16  = lane & 15;
    int m0 = blockIdx.x * 64 + wave * 16;
    int n0 = blockIdx.y * 128;
    int m  = m0 + l16;
    bool mvalid = (m < M);
    const unsigned short* xrow = xb + (size_t)m * IN_CH;

    f32x4 acc[8] = {};
    for (int k0 = 0; k0 < IN_CH; k0 += 32) {
        int k = k0 + quad * 8;
        bf16x8 a = {};
        if (mvalid) a = *(const bf16x8*)(xrow + k);
        #pragma unroll
        for (int t = 0; t < 8; t++) {
            int n = n0 + t * 16 + l16;
            bf16x8 b = *(const bf16x8*)(wb + (size_t)n * IN_CH + k);
            acc[t] = __builtin_amdgcn_mfma_f32_16x16x32_bf16(a, b, acc[t], 0, 0, 0);
        }
    }
    #pragma unroll
    for (int t = 0; t < 8; t++) {
        int col = n0 + t * 16 + l16;
        float bv = bias[col];
        #pragma unroll
        for (int r = 0; r < 4; r++) {
            int row = m0 + quad * 4 + r;
            if (row < M) {
                float v = acc[t][r] + bv;
                h0 [(size_t)row * OUT_CH + col] = v;
                h0b[(size_t)row * OUT_CH + col] = f2b(v);
            }
        }
    }
}

// ---------------- SpMM over bf16 features: one wave per node, lane owns 4 channels ----------
// y_i = sum_e norm_e * hb[col_e]   (fp32 accumulate)
// yb_out    : bf16 copy of y
// axpy_out  : fp32  prev + wts[widx]*y
// axpyb_out : bf16 (prev + wts[widx]*y)
__global__ __launch_bounds__(256) void spmm_kernel(const unsigned short* __restrict__ hb,
                                                   const int* __restrict__ offs,
                                                   const int* __restrict__ csr_col,
                                                   const float* __restrict__ csr_norm,
                                                   const float* __restrict__ prev,
                                                   const float* __restrict__ wts, int widx,
                                                   unsigned short* __restrict__ yb_out,
                                                   float* __restrict__ axpy_out,
                                                   unsigned short* __restrict__ axpyb_out, int n) {
    int wave = (blockIdx.x * blockDim.x + threadIdx.x) >> 6;
    int lane = threadIdx.x & 63;
    if (wave >= n) return;
    int s = offs[wave], e = offs[wave + 1];
    float a0 = 0.f, a1 = 0.f, a2 = 0.f, a3 = 0.f;
    int p = s;
    for (; p + 1 < e; p += 2) {
        int   c0 = csr_col[p],   c1 = csr_col[p + 1];
        float n0 = csr_norm[p],  n1 = csr_norm[p + 1];
        ushort4 v0 = ((const ushort4*)(hb + (size_t)c0 * OUT_CH))[lane];
        ushort4 v1 = ((const ushort4*)(hb + (size_t)c1 * OUT_CH))[lane];
        a0 += n0 * bf2f(v0.x) + n1 * bf2f(v1.x);
        a1 += n0 * bf2f(v0.y) + n1 * bf2f(v1.y);
        a2 += n0 * bf2f(v0.z) + n1 * bf2f(v1.z);
        a3 += n0 * bf2f(v0.w) + n1 * bf2f(v1.w);
    }
    if (p < e) {
        int   c0 = csr_col[p];
        float n0 = csr_norm[p];
        ushort4 v0 = ((const ushort4*)(hb + (size_t)c0 * OUT_CH))[lane];
        a0 += n0 * bf2f(v0.x);
        a1 += n0 * bf2f(v0.y);
        a2 += n0 * bf2f(v0.z);
        a3 += n0 * bf2f(v0.w);
    }
    size_t base = (size_t)wave * OUT_CH;
    if (yb_out) {
        ushort4 o;
        o.x = f2b(a0); o.y = f2b(a1); o.z = f2b(a2); o.w = f2b(a3);
        ((ushort4*)(yb_out + base))[lane] = o;
    }
    if (axpy_out || axpyb_out) {
        float wk = wts[widx];
        float4 pv = ((const float4*)(prev + base))[lane];
        float4 o;
        o.x = pv.x + wk * a0;
        o.y = pv.y + wk * a1;
        o.z = pv.z + wk * a2;
        o.w = pv.w + wk * a3;
        if (axpy_out) ((float4*)(axpy_out + base))[lane] = o;
        if (axpyb_out) {
            ushort4 ob;
            ob.x = f2b(o.x); ob.y = f2b(o.y); ob.z = f2b(o.z); ob.w = f2b(o.w);
            ((ushort4*)(axpyb_out + base))[lane] = ob;
        }
    }
}

extern "C" void kernel_launch(void* const* d_in, const int* in_sizes, int n_in,
                              void* d_out, int out_size, void* d_ws, size_t ws_size,
                              hipStream_t stream) {
    const float* x     = (const float*)d_in[0];
    const int*   ei    = (const int*)d_in[1];   // [2, E]
    const float* lin_w = (const float*)d_in[2]; // [OUT_CH, IN_CH]
    const float* lin_b = (const float*)d_in[3]; // [OUT_CH]
    const float* wts   = (const float*)d_in[4]; // [K]
    float* out = (float*)d_out;

    char* ws = (char*)d_ws;
    size_t off = 0;
    auto alloc = [&](size_t bytes) -> void* {
        void* p = ws + off;
        off += (bytes + 255) & ~(size_t)255;
        return p;
    };
    int*   deg      = (int*)  alloc(N_NODES * 4);
    int*   cursor   = (int*)  alloc(N_NODES * 4);
    int*   offs     = (int*)  alloc((N_NODES + 1) * 4);
    float* dinv     = (float*)alloc(N_NODES * 4);
    int*   csr_col  = (int*)  alloc((size_t)E_EDGES * 4);
    float* csr_norm = (float*)alloc((size_t)E_EDGES * 4);
    unsigned short* xb    = (unsigned short*)alloc((size_t)N_NODES * IN_CH * 2);
    unsigned short* wbuf  = (unsigned short*)alloc((size_t)OUT_CH * IN_CH * 2);
    float*          h0    = (float*)         alloc((size_t)N_NODES * OUT_CH * 4);
    unsigned short* h0b   = (unsigned short*)alloc((size_t)N_NODES * OUT_CH * 2);
    float*          out1  = (float*)         alloc((size_t)N_NODES * OUT_CH * 4);
    unsigned short* out1b = (unsigned short*)alloc((size_t)N_NODES * OUT_CH * 2);
    unsigned short* t2b   = (unsigned short*)alloc((size_t)N_NODES * OUT_CH * 2);

    hipMemsetAsync(deg, 0, N_NODES * 4, stream);
    hipMemsetAsync(cursor, 0, N_NODES * 4, stream);

    const int* row = ei;
    const int* col = ei + E_EDGES;

    deg_kernel<<<(E_EDGES + 255) / 256, 256, 0, stream>>>(row, deg, E_EDGES);
    dinv_kernel<<<(N_NODES + 255) / 256, 256, 0, stream>>>(deg, dinv, N_NODES);
    scan_kernel<<<1, 256, 0, stream>>>(deg, offs, N_NODES);
    scatter_kernel<<<(E_EDGES + 255) / 256, 256, 0, stream>>>(row, col, dinv, offs, cursor,
                                                              csr_col, csr_norm, E_EDGES);

    // bf16 conversions
    int x4 = (N_NODES * IN_CH) / 4;
    cvt_kernel<<<(x4 + 255) / 256, 256, 0, stream>>>(x, xb, x4);
    int w4 = (OUT_CH * IN_CH) / 4;
    cvt_kernel<<<(w4 + 255) / 256, 256, 0, stream>>>(lin_w, wbuf, w4);

    // GEMM: h0 = x @ w^T + b  (fp32 + bf16 copies)
    dim3 ggrid((N_NODES + 63) / 64, OUT_CH / 128);
    gemm_mfma<<<ggrid, 256, 0, stream>>>(xb, wbuf, lin_b, h0, h0b, N_NODES);

    int sgrid = (N_NODES + 3) / 4; // 4 waves/block
    // out1 = h0 + w0 * spmm(h0)          (fp32 + bf16)
    spmm_kernel<<<sgrid, 256, 0, stream>>>(h0b, offs, csr_col, csr_norm, h0, wts, 0,
                                           nullptr, out1, out1b, N_NODES);
    // t2 = spmm(out1)                     (bf16 only)
    spmm_kernel<<<sgrid, 256, 0, stream>>>(out1b, offs, csr_col, csr_norm, nullptr, wts, 0,
                                           t2b, nullptr, nullptr, N_NODES);
    // out = out1 + w1 * spmm(t2)          (fp32 final)
    spmm_kernel<<<sgrid, 256, 0, stream>>>(t2b, offs, csr_col, csr_norm, out1, wts, 1,
                                           nullptr, out, nullptr, N_NODES);
}

// Round 3
// 343.071 us; speedup vs baseline: 1.5489x; 1.1052x over previous
//
#include <hip/hip_runtime.h>

#define N_NODES 10000
#define E_EDGES 640000
#define IN_CH   512
#define OUT_CH  256

typedef short bf16x8 __attribute__((ext_vector_type(8)));
typedef float f32x4  __attribute__((ext_vector_type(4)));

__device__ __forceinline__ float bf2f(unsigned short u) {
    return __uint_as_float(((unsigned int)u) << 16);
}
__device__ __forceinline__ unsigned short f2b(float f) {
    unsigned int u = __float_as_uint(f);
    return (unsigned short)((u + 0x7FFFu + ((u >> 16) & 1u)) >> 16);
}

// ---------------- degree histogram ----------------
__global__ void deg_kernel(const int* __restrict__ row, int* __restrict__ deg, int E) {
    int e = blockIdx.x * blockDim.x + threadIdx.x;
    if (e < E) atomicAdd(&deg[row[e]], 1);
}

// ---------------- dinv = rsqrt(deg) ----------------
__global__ void dinv_kernel(const int* __restrict__ deg, float* __restrict__ dinv, int n) {
    int i = blockIdx.x * blockDim.x + threadIdx.x;
    if (i < n) {
        int d = deg[i];
        dinv[i] = (d > 0) ? rsqrtf((float)d) : 0.0f;
    }
}

// ---------------- single-block exclusive scan over deg -> offs[n+1] ----------------
__global__ void scan_kernel(const int* __restrict__ deg, int* __restrict__ offs, int n) {
    __shared__ int partial[256];
    int tid = threadIdx.x;
    int per = (n + 255) / 256;
    int start = tid * per;
    int end = start + per; if (end > n) end = n; if (start > n) start = n;
    int s = 0;
    for (int i = start; i < end; i++) s += deg[i];
    partial[tid] = s;
    __syncthreads();
    for (int off = 1; off < 256; off <<= 1) {
        int v = (tid >= off) ? partial[tid - off] : 0;
        __syncthreads();
        partial[tid] += v;
        __syncthreads();
    }
    int base = (tid == 0) ? 0 : partial[tid - 1];
    for (int i = start; i < end; i++) {
        offs[i] = base;
        base += deg[i];
    }
    if (tid == 255) offs[n] = partial[255];
}

// ---------------- scatter edges into CSR (packed col+norm, 8B) ----------------
__global__ void scatter_kernel(const int* __restrict__ row, const int* __restrict__ col,
                               const float* __restrict__ dinv, const int* __restrict__ offs,
                               int* __restrict__ cursor, int2* __restrict__ csr, int E) {
    int e = blockIdx.x * blockDim.x + threadIdx.x;
    if (e >= E) return;
    int r = row[e];
    int c = col[e];
    int p = offs[r] + atomicAdd(&cursor[r], 1);
    int2 q;
    q.x = c;
    q.y = __float_as_int(dinv[r] * dinv[c]);
    csr[p] = q;
}

// ---------------- bf16 MFMA GEMM with fused fp32->bf16 staging ----------------
// h0[m][n] = sum_k x[m][k]*w[n][k] + b[n].  Tile 64(M) x 128(N) x 64(K).
// 4 waves: wave owns rows [wave*16, wave*16+16) x all 128 cols (8 mfma tiles).
// A frag: lane holds A[m=l16][k=quad*8+j]; B frag: B[n=l16][k=quad*8+j].
// D layout: col=l16, row=quad*4+reg (m89-verified).
__global__ __launch_bounds__(256) void gemm_mfma(const float* __restrict__ x,
                                                 const float* __restrict__ w,
                                                 const float* __restrict__ bias,
                                                 float* __restrict__ h0,
                                                 unsigned short* __restrict__ h0b, int M) {
    __shared__ unsigned short As[64][72];   // +8 pad: frag ds_read_b128 is 2-way (free)
    __shared__ unsigned short Bs[128][72];
    int tid = threadIdx.x;
    int wave = tid >> 6, lane = tid & 63, quad = lane >> 4, l16 = lane & 15;
    int row0 = blockIdx.x * 64;
    int n0 = blockIdx.y * 128;

    int ar = tid >> 2;              // 0..63   (A row)
    int aseg = (tid & 3) * 16;      // 16-elem segment within 64-k row
    int br = tid >> 1;              // 0..127  (B row)
    int bseg = (tid & 1) * 32;      // 32-elem segment

    f32x4 acc[8] = {};
    for (int k0 = 0; k0 < IN_CH; k0 += 64) {
        // stage A tile (convert fp32 -> bf16 on the fly)
        {
            int gr = row0 + ar;
            if (gr < M) {
                const float4* src = (const float4*)(x + (size_t)gr * IN_CH + k0 + aseg);
                #pragma unroll
                for (int i = 0; i < 4; i++) {
                    float4 v = src[i];
                    ushort4 o;
                    o.x = f2b(v.x); o.y = f2b(v.y); o.z = f2b(v.z); o.w = f2b(v.w);
                    *(ushort4*)&As[ar][aseg + i * 4] = o;
                }
            } else {
                ushort4 z = {0, 0, 0, 0};
                #pragma unroll
                for (int i = 0; i < 4; i++) *(ushort4*)&As[ar][aseg + i * 4] = z;
            }
        }
        // stage B tile
        {
            const float4* src = (const float4*)(w + (size_t)(n0 + br) * IN_CH + k0 + bseg);
            #pragma unroll
            for (int i = 0; i < 8; i++) {
                float4 v = src[i];
                ushort4 o;
                o.x = f2b(v.x); o.y = f2b(v.y); o.z = f2b(v.z); o.w = f2b(v.w);
                *(ushort4*)&Bs[br][bseg + i * 4] = o;
            }
        }
        __syncthreads();
        #pragma unroll
        for (int kk = 0; kk < 2; kk++) {
            bf16x8 a = *(const bf16x8*)&As[wave * 16 + l16][kk * 32 + quad * 8];
            #pragma unroll
            for (int t = 0; t < 8; t++) {
                bf16x8 b = *(const bf16x8*)&Bs[t * 16 + l16][kk * 32 + quad * 8];
                acc[t] = __builtin_amdgcn_mfma_f32_16x16x32_bf16(a, b, acc[t], 0, 0, 0);
            }
        }
        __syncthreads();
    }
    #pragma unroll
    for (int t = 0; t < 8; t++) {
        int col = n0 + t * 16 + l16;
        float bv = bias[col];
        #pragma unroll
        for (int r = 0; r < 4; r++) {
            int grow = row0 + wave * 16 + quad * 4 + r;
            if (grow < M) {
                float v = acc[t][r] + bv;
                h0 [(size_t)grow * OUT_CH + col] = v;
                h0b[(size_t)grow * OUT_CH + col] = f2b(v);
            }
        }
    }
}

// ---------------- SpMM over bf16 features: one wave per node, 4x unrolled ----------
// y_i = sum_e norm_e * hb[col_e]   (fp32 accumulate)
__global__ __launch_bounds__(256) void spmm_kernel(const unsigned short* __restrict__ hb,
                                                   const int* __restrict__ offs,
                                                   const int2* __restrict__ csr,
                                                   const float* __restrict__ prev,
                                                   const float* __restrict__ wts, int widx,
                                                   unsigned short* __restrict__ yb_out,
                                                   float* __restrict__ axpy_out,
                                                   unsigned short* __restrict__ axpyb_out, int n) {
    int wave = (blockIdx.x * blockDim.x + threadIdx.x) >> 6;
    int lane = threadIdx.x & 63;
    if (wave >= n) return;
    int s = offs[wave], e = offs[wave + 1];
    float a0 = 0.f, a1 = 0.f, a2 = 0.f, a3 = 0.f;
    int p = s;
    for (; p + 3 < e; p += 4) {
        int2 q0 = csr[p];
        int2 q1 = csr[p + 1];
        int2 q2 = csr[p + 2];
        int2 q3 = csr[p + 3];
        ushort4 v0 = ((const ushort4*)(hb + (size_t)q0.x * OUT_CH))[lane];
        ushort4 v1 = ((const ushort4*)(hb + (size_t)q1.x * OUT_CH))[lane];
        ushort4 v2 = ((const ushort4*)(hb + (size_t)q2.x * OUT_CH))[lane];
        ushort4 v3 = ((const ushort4*)(hb + (size_t)q3.x * OUT_CH))[lane];
        float n0 = __int_as_float(q0.y), n1 = __int_as_float(q1.y);
        float n2 = __int_as_float(q2.y), n3 = __int_as_float(q3.y);
        a0 += n0 * bf2f(v0.x) + n1 * bf2f(v1.x) + n2 * bf2f(v2.x) + n3 * bf2f(v3.x);
        a1 += n0 * bf2f(v0.y) + n1 * bf2f(v1.y) + n2 * bf2f(v2.y) + n3 * bf2f(v3.y);
        a2 += n0 * bf2f(v0.z) + n1 * bf2f(v1.z) + n2 * bf2f(v2.z) + n3 * bf2f(v3.z);
        a3 += n0 * bf2f(v0.w) + n1 * bf2f(v1.w) + n2 * bf2f(v2.w) + n3 * bf2f(v3.w);
    }
    for (; p < e; p++) {
        int2 q0 = csr[p];
        float n0 = __int_as_float(q0.y);
        ushort4 v0 = ((const ushort4*)(hb + (size_t)q0.x * OUT_CH))[lane];
        a0 += n0 * bf2f(v0.x);
        a1 += n0 * bf2f(v0.y);
        a2 += n0 * bf2f(v0.z);
        a3 += n0 * bf2f(v0.w);
    }
    size_t base = (size_t)wave * OUT_CH;
    if (yb_out) {
        ushort4 o;
        o.x = f2b(a0); o.y = f2b(a1); o.z = f2b(a2); o.w = f2b(a3);
        ((ushort4*)(yb_out + base))[lane] = o;
    }
    if (axpy_out || axpyb_out) {
        float wk = wts[widx];
        float4 pv = ((const float4*)(prev + base))[lane];
        float4 o;
        o.x = pv.x + wk * a0;
        o.y = pv.y + wk * a1;
        o.z = pv.z + wk * a2;
        o.w = pv.w + wk * a3;
        if (axpy_out) ((float4*)(axpy_out + base))[lane] = o;
        if (axpyb_out) {
            ushort4 ob;
            ob.x = f2b(o.x); ob.y = f2b(o.y); ob.z = f2b(o.z); ob.w = f2b(o.w);
            ((ushort4*)(axpyb_out + base))[lane] = ob;
        }
    }
}

extern "C" void kernel_launch(void* const* d_in, const int* in_sizes, int n_in,
                              void* d_out, int out_size, void* d_ws, size_t ws_size,
                              hipStream_t stream) {
    const float* x     = (const float*)d_in[0];
    const int*   ei    = (const int*)d_in[1];   // [2, E]
    const float* lin_w = (const float*)d_in[2]; // [OUT_CH, IN_CH]
    const float* lin_b = (const float*)d_in[3]; // [OUT_CH]
    const float* wts   = (const float*)d_in[4]; // [K]
    float* out = (float*)d_out;

    char* ws = (char*)d_ws;
    size_t off = 0;
    auto alloc = [&](size_t bytes) -> void* {
        void* p = ws + off;
        off += (bytes + 255) & ~(size_t)255;
        return p;
    };
    int*   deg      = (int*)  alloc(N_NODES * 4 * 2); // deg + cursor contiguous (one memset)
    int*   cursor   = deg + N_NODES;
    int*   offs     = (int*)  alloc((N_NODES + 1) * 4);
    float* dinv     = (float*)alloc(N_NODES * 4);
    int2*  csr      = (int2*) alloc((size_t)E_EDGES * 8);
    float*          h0    = (float*)         alloc((size_t)N_NODES * OUT_CH * 4);
    unsigned short* h0b   = (unsigned short*)alloc((size_t)N_NODES * OUT_CH * 2);
    float*          out1  = (float*)         alloc((size_t)N_NODES * OUT_CH * 4);
    unsigned short* out1b = (unsigned short*)alloc((size_t)N_NODES * OUT_CH * 2);
    unsigned short* t2b   = (unsigned short*)alloc((size_t)N_NODES * OUT_CH * 2);

    hipMemsetAsync(deg, 0, N_NODES * 4 * 2, stream);

    const int* row = ei;
    const int* col = ei + E_EDGES;

    deg_kernel<<<(E_EDGES + 255) / 256, 256, 0, stream>>>(row, deg, E_EDGES);
    dinv_kernel<<<(N_NODES + 255) / 256, 256, 0, stream>>>(deg, dinv, N_NODES);
    scan_kernel<<<1, 256, 0, stream>>>(deg, offs, N_NODES);
    scatter_kernel<<<(E_EDGES + 255) / 256, 256, 0, stream>>>(row, col, dinv, offs, cursor,
                                                              csr, E_EDGES);

    // GEMM: h0 = x @ w^T + b  (fp32 + bf16 copies), conversion fused
    dim3 ggrid((N_NODES + 63) / 64, OUT_CH / 128);
    gemm_mfma<<<ggrid, 256, 0, stream>>>(x, lin_w, lin_b, h0, h0b, N_NODES);

    int sgrid = (N_NODES + 3) / 4; // 4 waves/block
    // out1 = h0 + w0 * spmm(h0)          (fp32 + bf16)
    spmm_kernel<<<sgrid, 256, 0, stream>>>(h0b, offs, csr, h0, wts, 0,
                                           nullptr, out1, out1b, N_NODES);
    // t2 = spmm(out1)                     (bf16 only)
    spmm_kernel<<<sgrid, 256, 0, stream>>>(out1b, offs, csr, nullptr, wts, 0,
                                           t2b, nullptr, nullptr, N_NODES);
    // out = out1 + w1 * spmm(t2)          (fp32 final)
    spmm_kernel<<<sgrid, 256, 0, stream>>>(t2b, offs, csr, out1, wts, 1,
                                           nullptr, out, nullptr, N_NODES);
}